// Round 1
// baseline (394.107 us; speedup 1.0000x reference)
//
#include <hip/hip_runtime.h>
#include <math.h>

#define Bn 64
#define Tn 2048
#define ENC 512
#define ATT 128
#define RNN 1024
#define NF 32
#define KS 31
#define WINR 32
#define WSZ 65          // window positions: 2*WINR + 1
#define HALO 95         // WSZ + KS - 1

// One block per batch row. Everything outside the 65-wide window has
// softmax weight exactly 0 (exp(-1e9 - m) underflows in fp32), so we only
// compute conv/tanh/softmax/context inside the window.
__global__ __launch_bounds__(256)
void attn_win_kernel(
    const float* __restrict__ hidden,        // [B, RNN]
    const float* __restrict__ memory,        // [B, T, ENC]
    const float* __restrict__ pmem,          // [B, T, ATT]
    const float* __restrict__ cat,           // [B, 2, T]
    const unsigned char* __restrict__ mask,  // [B, T] bool
    const int*  __restrict__ mlen,           // [B]
    const float* __restrict__ cpos,          // [B]
    const float* __restrict__ convw,         // [NF, 2, KS]
    const float* __restrict__ densew,        // [ATT, NF]
    const float* __restrict__ qw,            // [ATT, RNN]
    const float* __restrict__ vw,            // [1, ATT]
    const float* __restrict__ posoff,        // [1]
    float* __restrict__ out)                 // ctx[B*ENC] | w[B*T] | newpos[B]
{
    __shared__ float s_hidden[RNN];        // 4 KB
    __shared__ float s_part[256];
    __shared__ float s_qproj[ATT];
    __shared__ float s_ldw[ATT * 33];      // densew padded (stride 33 -> conflict-free)
    __shared__ float s_cw[NF * 2 * KS];
    __shared__ float s_cat[2 * HALO];
    __shared__ float s_conv[WSZ * NF];     // conv[j*NF + f]
    __shared__ float s_align[WSZ];
    __shared__ float s_w[WSZ];

    const int b = blockIdx.x;
    const int tid = threadIdx.x;

    // ---- window start (all threads, uniform scalar math) ----
    float cp = cpos[b] + posoff[0];
    float mend = (float)(mlen[b] - 1 - WINR);
    cp = fminf(fmaxf(cp, (float)WINR), mend);
    int s = (int)rintf(fmaxf(cp - (float)WINR, 0.0f));  // round-half-even == np.round
    if (s < 0) s = 0;
    if (s > Tn - WSZ) s = Tn - WSZ;   // defensive; unreachable for valid inputs

    // ---- stage inputs to LDS ----
    for (int i = tid; i < RNN; i += 256) s_hidden[i] = hidden[(size_t)b * RNN + i];
    for (int i = tid; i < ATT * NF; i += 256) {
        int a = i >> 5, f = i & 31;
        s_ldw[a * 33 + f] = densew[i];
    }
    for (int i = tid; i < NF * 2 * KS; i += 256) s_cw[i] = convw[i];
    for (int i = tid; i < 2 * HALO; i += 256) {
        int c = i / HALO, j = i - c * HALO;
        int t = s - (KS - 1) / 2 + j;
        float v = 0.0f;
        if (t >= 0 && t < Tn) v = cat[((size_t)b * 2 + c) * Tn + t];
        s_cat[c * HALO + j] = v;
    }
    __syncthreads();

    // ---- query projection: a = tid&127, half-K split over thread pairs ----
    {
        int a = tid & 127, half = tid >> 7;
        const float4* q4 = (const float4*)(qw + (size_t)a * RNN + half * 512);
        const float4* h4 = (const float4*)(s_hidden + half * 512);
        float acc = 0.0f;
#pragma unroll 4
        for (int i = 0; i < 128; i++) {
            float4 q = q4[i], h = h4[i];
            acc += q.x * h.x + q.y * h.y + q.z * h.z + q.w * h.w;
        }
        s_part[tid] = acc;
    }
    __syncthreads();
    if (tid < ATT) s_qproj[tid] = s_part[tid] + s_part[tid + 128];

    // ---- location conv over window: 65*32 tasks ----
    for (int i = tid; i < WSZ * NF; i += 256) {
        int j = i >> 5, f = i & 31;
        const float* w0 = s_cw + f * 2 * KS;
        const float* c0 = s_cat + j;
        const float* c1 = s_cat + HALO + j;
        float acc = 0.0f;
#pragma unroll
        for (int k = 0; k < KS; k++) acc += c0[k] * w0[k] + c1[k] * w0[KS + k];
        s_conv[i] = acc;
    }
    __syncthreads();

    // ---- alignment[j] = sum_a tanh(conv.densew + qproj + pmem) * v[a] ----
    const int lane = tid & 63;
    const int wv = tid >> 6;
    const float va0 = vw[lane];
    const float va1 = vw[lane + 64];
    for (int j = wv; j < WSZ; j += 4) {
        int t = s + j;
        const float* pm = pmem + ((size_t)b * Tn + t) * ATT;
        const float* cv = s_conv + j * NF;
        const float* l0 = s_ldw + lane * 33;
        const float* l1 = s_ldw + (lane + 64) * 33;
        float x0 = s_qproj[lane] + pm[lane];
        float x1 = s_qproj[lane + 64] + pm[lane + 64];
#pragma unroll
        for (int f = 0; f < NF; f++) {
            float c = cv[f];
            x0 += c * l0[f];
            x1 += c * l1[f];
        }
        float val = tanhf(x0) * va0 + tanhf(x1) * va1;
        for (int off = 32; off > 0; off >>= 1) val += __shfl_down(val, off);
        if (lane == 0) {
            bool mk = mask[(size_t)b * Tn + t] != 0;
            s_align[j] = mk ? -1e9f : val;
        }
    }
    __syncthreads();

    // ---- softmax over the 65-wide window ----
    if (tid < WSZ) {
        float m = -1e30f;
        for (int j = 0; j < WSZ; j++) m = fmaxf(m, s_align[j]);
        float sum = 0.0f;
        for (int j = 0; j < WSZ; j++) sum += expf(s_align[j] - m);
        s_w[tid] = expf(s_align[tid] - m) / sum;
    }
    __syncthreads();

    // ---- new_pos ----
    if (tid == 0) {
        float np = 0.0f;
        for (int j = 0; j < WSZ; j++) np += s_w[j] * (float)(s + j);
        out[(size_t)Bn * ENC + (size_t)Bn * Tn + b] = np;
    }

    // ---- attention_weights row: zeros outside window ----
    {
        float4* wout = (float4*)(out + (size_t)Bn * ENC + (size_t)b * Tn);
        for (int i = tid; i < Tn / 4; i += 256) {
            float4 v;
            float* vv = (float*)&v;
#pragma unroll
            for (int q = 0; q < 4; q++) {
                int j = i * 4 + q - s;
                vv[q] = (j >= 0 && j < WSZ) ? s_w[j] : 0.0f;
            }
            wout[i] = v;
        }
    }

    // ---- context: 65-row weighted sum of memory, float2 per thread ----
    {
        const float2* m2 = (const float2*)(memory + (size_t)b * Tn * ENC);
        float2 acc = make_float2(0.0f, 0.0f);
        for (int j = 0; j < WSZ; j++) {
            float wj = s_w[j];
            float2 mv = m2[(size_t)(s + j) * (ENC / 2) + tid];
            acc.x += wj * mv.x;
            acc.y += wj * mv.y;
        }
        ((float2*)out)[(size_t)b * (ENC / 2) + tid] = acc;
    }
}

extern "C" void kernel_launch(void* const* d_in, const int* in_sizes, int n_in,
                              void* d_out, int out_size, void* d_ws, size_t ws_size,
                              hipStream_t stream) {
    attn_win_kernel<<<Bn, 256, 0, stream>>>(
        (const float*)d_in[0],          // attention_hidden_state
        (const float*)d_in[1],          // memory
        (const float*)d_in[2],          // processed_memory
        (const float*)d_in[3],          // attention_weights_cat
        (const unsigned char*)d_in[4],  // mask (bool)
        (const int*)d_in[5],            // memory_lengths
        (const float*)d_in[6],          // current_pos
        (const float*)d_in[7],          // loc_conv_w
        (const float*)d_in[8],          // loc_dense_w
        (const float*)d_in[9],          // query_w
        (const float*)d_in[10],         // v_w
        (const float*)d_in[11],         // pos_offset
        (float*)d_out);
}

// Round 2
// 381.205 us; speedup vs baseline: 1.0338x; 1.0338x over previous
//
#include <hip/hip_runtime.h>
#include <math.h>

#define Bn 64
#define Tn 2048
#define ENC 512
#define ATT 128
#define RNN 1024
#define NF 32
#define KS 31
#define WINR 32
#define WSZ 65          // window positions: 2*WINR + 1
#define HALO 95         // WSZ + KS - 1
#define WPAD 68         // padded per-b stride for ws weights

// Everything outside the 65-wide window has softmax weight exactly 0
// (exp(-1e9 - m) underflows in fp32), so only the window needs computing.
//
// K1: one block per batch (512 thr, 8 waves): window start, query proj,
//     location conv, tanh-dot alignment (pmem staged to LDS in bulk),
//     softmax, weights row, new_pos; weights + s stashed to ws for K2.
// K2: 4 blocks per batch: context = 65-row weighted sum of memory,
//     spread across 256 blocks for full-chip BW on the cold reads.

__global__ __launch_bounds__(512)
void attn_stage1(
    const float* __restrict__ hidden,        // [B, RNN]
    const float* __restrict__ pmem,          // [B, T, ATT]
    const float* __restrict__ cat,           // [B, 2, T]
    const unsigned char* __restrict__ mask,  // [B, T] bool
    const int*  __restrict__ mlen,           // [B]
    const float* __restrict__ cpos,          // [B]
    const float* __restrict__ convw,         // [NF, 2, KS]
    const float* __restrict__ densew,        // [ATT, NF]
    const float* __restrict__ qw,            // [ATT, RNN]
    const float* __restrict__ vw,            // [1, ATT]
    const float* __restrict__ posoff,        // [1]
    float* __restrict__ out,                 // ctx[B*ENC] | w[B*T] | newpos[B]
    float* __restrict__ ws_w,                // [B, WPAD]
    int*   __restrict__ ws_s)                // [B]
{
    __shared__ float s_hidden[RNN];          // 4 KB
    __shared__ float s_part[512];
    __shared__ float s_qproj[ATT];
    __shared__ float s_ldw[ATT * 33];        // densew padded -> conflict-free
    __shared__ float s_cw[NF * 2 * KS];
    __shared__ float s_cat[2 * HALO];
    __shared__ float s_conv[WSZ * NF];
    __shared__ float s_pm[WSZ * ATT];        // 33 KB pmem window
    __shared__ float s_align[WSZ];
    __shared__ float s_w[WSZ];

    const int b = blockIdx.x;
    const int tid = threadIdx.x;

    // ---- window start (uniform scalar math; rintf == np.round half-even) ----
    float cp = cpos[b] + posoff[0];
    float mend = (float)(mlen[b] - 1 - WINR);
    cp = fminf(fmaxf(cp, (float)WINR), mend);
    int s = (int)rintf(fmaxf(cp - (float)WINR, 0.0f));
    if (s < 0) s = 0;
    if (s > Tn - WSZ) s = Tn - WSZ;          // defensive; unreachable normally

    // ---- bulk stage to LDS (all loads independent -> pipelined) ----
    for (int i = tid; i < RNN / 4; i += 512)
        ((float4*)s_hidden)[i] = ((const float4*)(hidden + (size_t)b * RNN))[i];
    // pmem window is one contiguous 8320-float span (512B-aligned base)
    {
        const float4* pmw = (const float4*)(pmem + ((size_t)b * Tn + s) * ATT);
        for (int i = tid; i < WSZ * ATT / 4; i += 512)
            ((float4*)s_pm)[i] = pmw[i];
    }
    for (int i = tid; i < ATT * NF; i += 512) {
        int a = i >> 5, f = i & 31;
        s_ldw[a * 33 + f] = densew[i];
    }
    for (int i = tid; i < NF * 2 * KS; i += 512) s_cw[i] = convw[i];
    for (int i = tid; i < 2 * HALO; i += 512) {
        int c = i / HALO, j = i - c * HALO;
        int t = s - (KS - 1) / 2 + j;
        float v = 0.0f;
        if (t >= 0 && t < Tn) v = cat[((size_t)b * 2 + c) * Tn + t];
        s_cat[c * HALO + j] = v;
    }
    __syncthreads();

    // ---- query projection: a = tid&127, quarter-K split (256 each) ----
    {
        int a = tid & 127, q = tid >> 7;
        const float4* q4 = (const float4*)(qw + (size_t)a * RNN + q * 256);
        const float4* h4 = (const float4*)(s_hidden + q * 256);
        float acc = 0.0f;
#pragma unroll 8
        for (int i = 0; i < 64; i++) {
            float4 x = q4[i], h = h4[i];
            acc += x.x * h.x + x.y * h.y + x.z * h.z + x.w * h.w;
        }
        s_part[tid] = acc;
    }
    __syncthreads();
    if (tid < ATT)
        s_qproj[tid] = s_part[tid] + s_part[tid + 128] + s_part[tid + 256] + s_part[tid + 384];

    // ---- location conv over window: 65*32 tasks (doesn't touch s_qproj) ----
    for (int i = tid; i < WSZ * NF; i += 512) {
        int j = i >> 5, f = i & 31;
        const float* w0 = s_cw + f * 2 * KS;
        const float* c0 = s_cat + j;
        const float* c1 = s_cat + HALO + j;
        float acc = 0.0f;
#pragma unroll
        for (int k = 0; k < KS; k++) acc += c0[k] * w0[k] + c1[k] * w0[KS + k];
        s_conv[i] = acc;
    }
    __syncthreads();

    // ---- alignment[j]: one wave per j, lanes cover dims (lane, lane+64) ----
    const int lane = tid & 63;
    const int wv = tid >> 6;
    const float va0 = vw[lane];
    const float va1 = vw[lane + 64];
    for (int j = wv; j < WSZ; j += 8) {
        const float* pmr = s_pm + j * ATT;
        const float* cv = s_conv + j * NF;
        const float* l0 = s_ldw + lane * 33;
        const float* l1 = s_ldw + (lane + 64) * 33;
        float x0 = s_qproj[lane] + pmr[lane];
        float x1 = s_qproj[lane + 64] + pmr[lane + 64];
#pragma unroll
        for (int f = 0; f < NF; f++) {
            float c = cv[f];
            x0 += c * l0[f];
            x1 += c * l1[f];
        }
        float val = tanhf(x0) * va0 + tanhf(x1) * va1;
        for (int off = 32; off > 0; off >>= 1) val += __shfl_down(val, off);
        if (lane == 0) {
            bool mk = mask[(size_t)b * Tn + s + j] != 0;
            s_align[j] = mk ? -1e9f : val;
        }
    }
    __syncthreads();

    // ---- softmax over the 65-wide window ----
    if (tid < WSZ) {
        float m = -1e30f;
        for (int j = 0; j < WSZ; j++) m = fmaxf(m, s_align[j]);
        float sum = 0.0f;
        for (int j = 0; j < WSZ; j++) sum += expf(s_align[j] - m);
        s_w[tid] = expf(s_align[tid] - m) / sum;
    }
    __syncthreads();

    // ---- new_pos + stash window state for K2 ----
    if (tid == 0) {
        float np = 0.0f;
        for (int j = 0; j < WSZ; j++) np += s_w[j] * (float)(s + j);
        out[(size_t)Bn * ENC + (size_t)Bn * Tn + b] = np;
        ws_s[b] = s;
    }
    if (tid < WSZ) ws_w[b * WPAD + tid] = s_w[tid];

    // ---- attention_weights row: zeros outside window ----
    {
        float4* wout = (float4*)(out + (size_t)Bn * ENC + (size_t)b * Tn);
        for (int i = tid; i < Tn / 4; i += 512) {
            float4 v;
            float* vv = (float*)&v;
#pragma unroll
            for (int q = 0; q < 4; q++) {
                int j = i * 4 + q - s;
                vv[q] = (j >= 0 && j < WSZ) ? s_w[j] : 0.0f;
            }
            wout[i] = v;
        }
    }
}

// context: 4 blocks per batch, each covers 128 enc dims; 65 independent
// row loads pipelined, full-chip spread for the cold memory-window reads.
__global__ __launch_bounds__(128)
void attn_ctx(
    const float* __restrict__ memory,        // [B, T, ENC]
    const float* __restrict__ ws_w,          // [B, WPAD]
    const int*  __restrict__ ws_s,           // [B]
    float* __restrict__ out)                 // ctx at offset 0
{
    __shared__ float s_w[WSZ];
    __shared__ int s_sv;
    const int b = blockIdx.x >> 2;
    const int r = blockIdx.x & 3;
    const int tid = threadIdx.x;
    if (tid < WSZ) s_w[tid] = ws_w[b * WPAD + tid];
    if (tid == 0) s_sv = ws_s[b];
    __syncthreads();
    const int s = s_sv;
    const float* mb = memory + (size_t)b * Tn * ENC + r * 128 + tid;
    float acc = 0.0f;
#pragma unroll 5
    for (int j = 0; j < WSZ; j++)
        acc += s_w[j] * mb[(size_t)(s + j) * ENC];
    out[(size_t)b * ENC + r * 128 + tid] = acc;
}

extern "C" void kernel_launch(void* const* d_in, const int* in_sizes, int n_in,
                              void* d_out, int out_size, void* d_ws, size_t ws_size,
                              hipStream_t stream) {
    float* ws_w = (float*)d_ws;                          // [B][WPAD] floats
    int*   ws_s = (int*)((char*)d_ws + Bn * WPAD * 4);   // [B] ints

    attn_stage1<<<Bn, 512, 0, stream>>>(
        (const float*)d_in[0],          // attention_hidden_state
        (const float*)d_in[2],          // processed_memory
        (const float*)d_in[3],          // attention_weights_cat
        (const unsigned char*)d_in[4],  // mask (bool)
        (const int*)d_in[5],            // memory_lengths
        (const float*)d_in[6],          // current_pos
        (const float*)d_in[7],          // loc_conv_w
        (const float*)d_in[8],          // loc_dense_w
        (const float*)d_in[9],          // query_w
        (const float*)d_in[10],         // v_w
        (const float*)d_in[11],         // pos_offset
        (float*)d_out, ws_w, ws_s);

    attn_ctx<<<Bn * 4, 128, 0, stream>>>(
        (const float*)d_in[1],          // memory
        ws_w, ws_s, (float*)d_out);
}

// Round 3
// 376.237 us; speedup vs baseline: 1.0475x; 1.0132x over previous
//
#include <hip/hip_runtime.h>
#include <math.h>

#define Bn 64
#define Tn 2048
#define ENC 512
#define ATT 128
#define RNN 1024
#define NF 32
#define KS 31
#define WINR 32
#define WSZ 65          // window positions: 2*WINR + 1
#define HALO 95         // WSZ + KS - 1
#define NTH 512

// Fully fused: everything outside the 65-wide window has softmax weight
// exactly 0 (exp(-1e9 - m) underflows in fp32). One block per batch.
// The context window of `memory` (133 KB) is prefetched into registers
// (33 float2/thread) in the same streaming pass as the pmem/hidden staging,
// since window start s depends only on cpos/mlen/posoff — the weighted
// sum is applied after softmax with zero extra global traffic.
__global__ __launch_bounds__(NTH)
void attn_fused(
    const float* __restrict__ hidden,        // [B, RNN]
    const float* __restrict__ memory,        // [B, T, ENC]
    const float* __restrict__ pmem,          // [B, T, ATT]
    const float* __restrict__ cat,           // [B, 2, T]
    const unsigned char* __restrict__ mask,  // [B, T] bool
    const int*  __restrict__ mlen,           // [B]
    const float* __restrict__ cpos,          // [B]
    const float* __restrict__ convw,         // [NF, 2, KS]
    const float* __restrict__ densew,        // [ATT, NF]
    const float* __restrict__ qw,            // [ATT, RNN]
    const float* __restrict__ vw,            // [1, ATT]
    const float* __restrict__ posoff,        // [1]
    float* __restrict__ out)                 // ctx[B*ENC] | w[B*T] | newpos[B]
{
    __shared__ float s_hidden[RNN];          // 4 KB
    __shared__ float s_part[NTH];
    __shared__ float s_qproj[ATT];
    __shared__ float s_ldw[ATT * 33];        // densew padded -> conflict-free
    __shared__ float s_cw[NF * 2 * KS];
    __shared__ float s_cat[2 * HALO];
    __shared__ float s_conv[WSZ * NF];
    __shared__ float s_pm[WSZ * ATT];        // 33 KB pmem window
    __shared__ unsigned char s_mk[WSZ];
    __shared__ float s_align[WSZ];
    __shared__ float s_w[WSZ];
    __shared__ float2 s_red[2 * (ENC / 2)]; // 4 KB ctx partials

    const int b = blockIdx.x;
    const int tid = threadIdx.x;

    // ---- window start (uniform scalar; rintf == np.round half-even) ----
    float cp = cpos[b] + posoff[0];
    float mend = (float)(mlen[b] - 1 - WINR);
    cp = fminf(fmaxf(cp, (float)WINR), mend);
    int s = (int)rintf(fmaxf(cp - (float)WINR, 0.0f));
    if (s < 0) s = 0;
    if (s > Tn - WSZ) s = Tn - WSZ;          // defensive; unreachable normally

    // ---- stage small inputs to LDS (independent loads -> pipelined) ----
    for (int i = tid; i < RNN / 4; i += NTH)
        ((float4*)s_hidden)[i] = ((const float4*)(hidden + (size_t)b * RNN))[i];
    {   // pmem window: one contiguous 8320-float span, 512B-aligned base
        const float4* pmw = (const float4*)(pmem + ((size_t)b * Tn + s) * ATT);
        for (int i = tid; i < WSZ * ATT / 4; i += NTH)
            ((float4*)s_pm)[i] = pmw[i];
    }
    for (int i = tid; i < ATT * NF; i += NTH) {
        int a = i >> 5, f = i & 31;
        s_ldw[a * 33 + f] = densew[i];
    }
    for (int i = tid; i < NF * 2 * KS; i += NTH) s_cw[i] = convw[i];
    for (int i = tid; i < 2 * HALO; i += NTH) {
        int cch = i / HALO, j = i - cch * HALO;
        int t = s - (KS - 1) / 2 + j;
        float v = 0.0f;
        if (t >= 0 && t < Tn) v = cat[((size_t)b * 2 + cch) * Tn + t];
        s_cat[cch * HALO + j] = v;
    }
    if (tid < WSZ) s_mk[tid] = mask[(size_t)b * Tn + s + tid];

    // ---- context-window prefetch into registers (consumed last) ----
    // thread -> enc float2 index c = tid&255, row group g = tid>>8 (wave-uniform)
    const int c = tid & 255;
    const int g = tid >> 8;
    float2 v[33];
    const float2* m2 = (const float2*)(memory + (size_t)b * Tn * ENC)
                       + (size_t)(s + g) * (ENC / 2) + c;
#pragma unroll
    for (int i = 0; i < 33; i++) {
        int j = g + 2 * i;
        if (j < WSZ) v[i] = m2[(size_t)(2 * i) * (ENC / 2)];
    }
    __syncthreads();

    // ---- query projection: a = tid&127, quarter-K split (256 each) ----
    {
        int a = tid & 127, q = tid >> 7;
        const float4* q4 = (const float4*)(qw + (size_t)a * RNN + q * 256);
        const float4* h4 = (const float4*)(s_hidden + q * 256);
        float acc = 0.0f;
#pragma unroll 8
        for (int i = 0; i < 64; i++) {
            float4 x = q4[i], h = h4[i];
            acc += x.x * h.x + x.y * h.y + x.z * h.z + x.w * h.w;
        }
        s_part[tid] = acc;
    }
    __syncthreads();
    if (tid < ATT)
        s_qproj[tid] = s_part[tid] + s_part[tid + 128] + s_part[tid + 256] + s_part[tid + 384];

    // ---- location conv over window: 65*32 tasks (doesn't touch s_qproj) ----
    for (int i = tid; i < WSZ * NF; i += NTH) {
        int j = i >> 5, f = i & 31;
        const float* w0 = s_cw + f * 2 * KS;
        const float* c0 = s_cat + j;
        const float* c1 = s_cat + HALO + j;
        float acc = 0.0f;
#pragma unroll
        for (int k = 0; k < KS; k++) acc += c0[k] * w0[k] + c1[k] * w0[KS + k];
        s_conv[i] = acc;
    }
    __syncthreads();

    // ---- alignment[j]: one wave per j, lanes cover dims (lane, lane+64) ----
    const int lane = tid & 63;
    const int wv = tid >> 6;
    const float va0 = vw[lane];
    const float va1 = vw[lane + 64];
    for (int j = wv; j < WSZ; j += 8) {
        const float* pmr = s_pm + j * ATT;
        const float* cv = s_conv + j * NF;
        const float* l0 = s_ldw + lane * 33;
        const float* l1 = s_ldw + (lane + 64) * 33;
        float x0 = s_qproj[lane] + pmr[lane];
        float x1 = s_qproj[lane + 64] + pmr[lane + 64];
#pragma unroll
        for (int f = 0; f < NF; f++) {
            float cc = cv[f];
            x0 += cc * l0[f];
            x1 += cc * l1[f];
        }
        float val = tanhf(x0) * va0 + tanhf(x1) * va1;
        for (int off = 32; off > 0; off >>= 1) val += __shfl_down(val, off);
        if (lane == 0) s_align[j] = s_mk[j] ? -1e9f : val;
    }
    __syncthreads();

    // ---- softmax over the 65-wide window ----
    if (tid < WSZ) {
        float m = -1e30f;
        for (int j = 0; j < WSZ; j++) m = fmaxf(m, s_align[j]);
        float sum = 0.0f;
        for (int j = 0; j < WSZ; j++) sum += expf(s_align[j] - m);
        s_w[tid] = expf(s_align[tid] - m) / sum;
    }
    __syncthreads();

    // ---- new_pos ----
    if (tid == 0) {
        float np = 0.0f;
        for (int j = 0; j < WSZ; j++) np += s_w[j] * (float)(s + j);
        out[(size_t)Bn * ENC + (size_t)Bn * Tn + b] = np;
    }

    // ---- attention_weights row: zeros outside window ----
    {
        float4* wout = (float4*)(out + (size_t)Bn * ENC + (size_t)b * Tn);
        for (int i = tid; i < Tn / 4; i += NTH) {
            float4 vv;
            float* vp = (float*)&vv;
#pragma unroll
            for (int q = 0; q < 4; q++) {
                int j = i * 4 + q - s;
                vp[q] = (j >= 0 && j < WSZ) ? s_w[j] : 0.0f;
            }
            wout[i] = vv;
        }
    }

    // ---- context finalize: weighted sum of the prefetched registers ----
    {
        float2 acc = make_float2(0.0f, 0.0f);
#pragma unroll
        for (int i = 0; i < 33; i++) {
            int j = g + 2 * i;
            if (j < WSZ) {
                float wj = s_w[j];
                acc.x += wj * v[i].x;
                acc.y += wj * v[i].y;
            }
        }
        s_red[g * (ENC / 2) + c] = acc;
    }
    __syncthreads();
    if (tid < ENC / 2) {
        float2 a = s_red[tid], bb = s_red[(ENC / 2) + tid];
        float2 r = make_float2(a.x + bb.x, a.y + bb.y);
        ((float2*)out)[(size_t)b * (ENC / 2) + tid] = r;
    }
}

extern "C" void kernel_launch(void* const* d_in, const int* in_sizes, int n_in,
                              void* d_out, int out_size, void* d_ws, size_t ws_size,
                              hipStream_t stream) {
    attn_fused<<<Bn, NTH, 0, stream>>>(
        (const float*)d_in[0],          // attention_hidden_state
        (const float*)d_in[1],          // memory
        (const float*)d_in[2],          // processed_memory
        (const float*)d_in[3],          // attention_weights_cat
        (const unsigned char*)d_in[4],  // mask (bool)
        (const int*)d_in[5],            // memory_lengths
        (const float*)d_in[6],          // current_pos
        (const float*)d_in[7],          // loc_conv_w
        (const float*)d_in[8],          // loc_dense_w
        (const float*)d_in[9],          // query_w
        (const float*)d_in[10],         // v_w
        (const float*)d_in[11],         // pos_offset
        (float*)d_out);
}